// Round 1
// baseline (1292.831 us; speedup 1.0000x reference)
//
#include <hip/hip_runtime.h>
#include <cstdint>
#include <cstddef>

typedef _Float16 half8 __attribute__((ext_vector_type(8)));
typedef _Float16 half4 __attribute__((ext_vector_type(4)));
typedef float floatx4 __attribute__((ext_vector_type(4)));

namespace {
constexpr int kB = 256, kT = 512, kIN = 48, kOUT = 48, kSEAS = 24, kH = 128;
constexpr int kW = kT - kIN + 1;           // 465 windows
constexpr int kWO = kT - kOUT - kIN + 1;   // 417
constexpr int kNB = kW * kB;               // 119040 rows
constexpr int kMBLK = kNB / 16;            // 7440 row-blocks of 16
constexpr float kLOG2E = 1.44269504088896340736f;
}

#if __has_builtin(__builtin_amdgcn_exp2f)
#define FEXP2(x) __builtin_amdgcn_exp2f(x)
#else
#define FEXP2(x) exp2f(x)
#endif
#if __has_builtin(__builtin_amdgcn_rcpf)
#define FRCP(x) __builtin_amdgcn_rcpf(x)
#else
#define FRCP(x) (1.0f / (x))
#endif

// sigmoid in exp2-domain: fsig(y) = 1/(1+2^-y); pass y = x*log2(e) for sigmoid(x)
__device__ __forceinline__ float fsig(float y) { return FRCP(1.0f + FEXP2(-y)); }
__device__ __forceinline__ float ftanh(float x) { return 2.0f * fsig(2.0f * kLOG2E * x) - 1.0f; }

// ---------------- transpose train (B,T) -> (T,B) ----------------
__global__ void k_transpose(const float* __restrict__ train, float* __restrict__ trainT) {
  int t = blockIdx.x, b = threadIdx.x;
  trainT[t * kB + b] = train[b * kT + t];
}

// ---------------- exponential smoothing scan ----------------
// seas laid out [560][B] (rows 0..24 init, 25..535 scan, 536..559 extension); levs [512][B]
__global__ void k_es(const float* __restrict__ trainT, const float* __restrict__ levp,
                     const float* __restrict__ seasp, const float* __restrict__ inits,
                     float* __restrict__ seas, float* __restrict__ levs) {
  int b = threadIdx.x;
  float lev_sm = fsig(levp[0] * kLOG2E);
  float seas_sm = fsig(seasp[0] * kLOG2E);
  float s00 = expf(inits[0]);
  for (int s = 0; s < kSEAS; ++s) seas[s * kB + b] = expf(inits[s]);
  seas[kSEAS * kB + b] = s00;
  float lev = trainT[b] / s00;
  levs[b] = lev;
  for (int k = 0; k < kT - 1; ++k) {
    float x = trainT[(k + 1) * kB + b];
    float st = seas[(k + 1) * kB + b];
    float ln = lev_sm * (x / st) + (1.0f - lev_sm) * lev;
    seas[(k + kSEAS + 1) * kB + b] = seas_sm * (x / ln) + (1.0f - seas_sm) * st;
    levs[(k + 1) * kB + b] = ln;
    lev = ln;
  }
  for (int j = 0; j < kOUT - kSEAS; ++j)
    seas[(kT + kSEAS + j) * kB + b] = seas[(kT + j) * kB + b];
}

// ---------------- window build: win_in (f16, padded K=64) ----------------
__global__ void k_win_in(const float* __restrict__ trainT, const float* __restrict__ seas,
                         const float* __restrict__ levs, _Float16* __restrict__ win) {
  int w = blockIdx.x, b = threadIdx.x;
  float lv = levs[(kIN - 1 + w) * kB + b];
  _Float16* row = win + (size_t)(w * kB + b) * 64;
  for (int j = 0; j < kIN; ++j) {
    int t = w + j;
    float v = trainT[t * kB + b] / seas[t * kB + b] / lv;
    row[j] = (_Float16)v;
  }
  for (int j = kIN; j < 64; ++j) row[j] = (_Float16)0.0f;
}

// ---------------- window build: win_out == output 1 (fp32, exact) ----------------
__global__ void k_win_out(const float* __restrict__ trainT, const float* __restrict__ seas,
                          const float* __restrict__ levs, float* __restrict__ out1) {
  int wo = blockIdx.x, b = threadIdx.x;
  float lv = levs[(kIN - 1 + wo) * kB + b];
  float* row = out1 + (size_t)(wo * kB + b) * kOUT;
  for (int j = 0; j < kOUT; ++j) {
    int t = kIN + wo + j;
    row[j] = trainT[t * kB + b] / seas[t * kB + b] / lv;
  }
}

// ---------------- weight prep ----------------
// Gate-interleaved column perm: out col c: ct=c>>4, n16=c&15, gate=ct&3, wv=ct>>2
// -> original gate row = gate*128 + wv*16 + n16. Prescale: i,f,o by log2e, g by 2*log2e.
__global__ void k_prep_bias(const float* __restrict__ bih, const float* __restrict__ bhh,
                            float* __restrict__ dst) {
  int c = blockIdx.x * 256 + threadIdx.x;
  if (c >= 512) return;
  int ct = c >> 4, n16 = c & 15, g = ct & 3, wv = ct >> 2;
  int row = g * 128 + wv * 16 + n16;
  float sc = (g == 2) ? 2.0f * kLOG2E : kLOG2E;
  dst[c] = (bih[row] + bhh[row]) * sc;
}

// B-fragment layout: [ct][kb][lane][jj] ; value = W[row(n)][k], n=lane&15, k=kb*32+(lane>>4)*8+jj
__global__ void k_prep_frags(const float* __restrict__ Wsrc, _Float16* __restrict__ dst, int NT,
                             int KB, int Kreal, int srcld, int perm) {
  int idx = blockIdx.x * 256 + threadIdx.x;
  int total = NT * KB * 512;
  if (idx >= total) return;
  int jj = idx & 7;
  int lane = (idx >> 3) & 63;
  int kb = (idx >> 9) % KB;
  int ct = idx / (KB * 512);
  int n16 = lane & 15;
  int k = kb * 32 + ((lane >> 4) << 3) + jj;
  int row;
  float sc;
  if (perm) {
    int g = ct & 3, wv = ct >> 2;
    row = g * 128 + wv * 16 + n16;
    sc = (g == 2) ? 2.0f * kLOG2E : kLOG2E;
  } else {
    row = ct * 16 + n16;
    sc = 1.0f;
  }
  float v = (k < Kreal) ? Wsrc[row * srcld + k] * sc : 0.0f;
  dst[idx] = (_Float16)v;
}

// ---------------- generic MFMA GEMM over the NB rows ----------------
// MODE 0: out f16 D-fragment layout (pre-gates X); MODE 1: tanh -> f16 row-major (nl, A2=residual);
// MODE 2: f32 row-major to out3 (+dup rows<WO*B to out0) (sc)
template <int NT, int KB, int MODE>
__global__ __launch_bounds__(512) void k_gemm(const _Float16* __restrict__ A,
                                              const _Float16* __restrict__ A2, int Khalfs,
                                              const _Float16* __restrict__ Bfr,
                                              const float* __restrict__ bias,
                                              _Float16* __restrict__ outh,
                                              float* __restrict__ outf,
                                              float* __restrict__ outf2) {
  __shared__ _Float16 bsh[NT * KB * 512];
  int tid = threadIdx.x;
  {
    const uint4* src = (const uint4*)Bfr;
    uint4* dst = (uint4*)bsh;
    for (int i = tid; i < NT * KB * 64; i += 512) dst[i] = src[i];
  }
  __syncthreads();
  int wv = tid >> 6, lane = tid & 63;
  int mblk = blockIdx.x * 8 + wv;
  if (mblk >= kMBLK) return;
  int m = lane & 15, kq = lane >> 4;
  const _Float16* arow = A + (size_t)(mblk * 16 + m) * Khalfs + kq * 8;
  half8 af[KB];
#pragma unroll
  for (int kb = 0; kb < KB; ++kb) af[kb] = *(const half8*)(arow + kb * 32);
  if constexpr (MODE == 1) {
    const _Float16* arow2 = A2 + (size_t)(mblk * 16 + m) * Khalfs + kq * 8;
#pragma unroll
    for (int kb = 0; kb < KB; ++kb) {
      half8 a2 = *(const half8*)(arow2 + kb * 32);
      af[kb] += a2;
    }
  }
#pragma unroll
  for (int t0 = 0; t0 < NT; t0 += 2) {
    float b0 = bias[t0 * 16 + m];
    floatx4 acc0 = {b0, b0, b0, b0};
    floatx4 acc1 = {0.f, 0.f, 0.f, 0.f};
    if (t0 + 1 < NT) {
      float b1 = bias[(t0 + 1) * 16 + m];
      acc1 = (floatx4){b1, b1, b1, b1};
    }
#pragma unroll
    for (int kb = 0; kb < KB; ++kb) {
      half8 bf0 = *(const half8*)(&bsh[((t0 * KB + kb) * 64 + lane) * 8]);
      acc0 = __builtin_amdgcn_mfma_f32_16x16x32_f16(af[kb], bf0, acc0, 0, 0, 0);
      if (t0 + 1 < NT) {
        half8 bf1 = *(const half8*)(&bsh[(((t0 + 1) * KB + kb) * 64 + lane) * 8]);
        acc1 = __builtin_amdgcn_mfma_f32_16x16x32_f16(af[kb], bf1, acc1, 0, 0, 0);
      }
    }
    if constexpr (MODE == 0) {
      half4 h0 = {(_Float16)acc0[0], (_Float16)acc0[1], (_Float16)acc0[2], (_Float16)acc0[3]};
      *(half4*)(outh + (((size_t)mblk * NT + t0) * 64 + lane) * 4) = h0;
      if (t0 + 1 < NT) {
        half4 h1 = {(_Float16)acc1[0], (_Float16)acc1[1], (_Float16)acc1[2], (_Float16)acc1[3]};
        *(half4*)(outh + (((size_t)mblk * NT + (t0 + 1)) * 64 + lane) * 4) = h1;
      }
    } else if constexpr (MODE == 1) {
#pragma unroll
      for (int r = 0; r < 4; ++r) {
        int row = mblk * 16 + kq * 4 + r;
        outh[(size_t)row * kH + t0 * 16 + m] = (_Float16)ftanh(acc0[r]);
        if (t0 + 1 < NT) outh[(size_t)row * kH + (t0 + 1) * 16 + m] = (_Float16)ftanh(acc1[r]);
      }
    } else {
#pragma unroll
      for (int r = 0; r < 4; ++r) {
        int row = mblk * 16 + kq * 4 + r;
        float v0 = acc0[r];
        outf[(size_t)row * kOUT + t0 * 16 + m] = v0;
        if (row < kWO * kB) outf2[(size_t)row * kOUT + t0 * 16 + m] = v0;
        if (t0 + 1 < NT) {
          float v1 = acc1[r];
          outf[(size_t)row * kOUT + (t0 + 1) * 16 + m] = v1;
          if (row < kWO * kB) outf2[(size_t)row * kOUT + (t0 + 1) * 16 + m] = v1;
        }
      }
    }
  }
}

// ---------------- recurrent LSTM kernel ----------------
// grid = d*16 WGs; WG = (kd = bid>>4, ib = bid&15) handles batches [ib*16,ib*16+16) of fold-offset kd.
// 8 waves; wave wv owns gate-cols [wv*64, wv*64+64) = ctiles wv*4+{i,f,g,o}; W_hh frags in VGPRs.
// h round-trips via XOR-swizzled LDS tile (granule g' = g ^ row) to form next-step A-fragments.
__global__ __launch_bounds__(512) void k_rec(const _Float16* __restrict__ Xfr,
                                             const _Float16* __restrict__ Whhf,
                                             _Float16* __restrict__ Hout, int d) {
  __shared__ _Float16 hbuf[2][2048];
  int tid = threadIdx.x, wv = tid >> 6, lane = tid & 63;
  int kd = blockIdx.x >> 4, ib = blockIdx.x & 15;
  int m = lane & 15, kq = lane >> 4;
  half8 whf[4][4];
#pragma unroll
  for (int g = 0; g < 4; ++g)
#pragma unroll
    for (int kb = 0; kb < 4; ++kb)
      whf[g][kb] = *(const half8*)(Whhf + ((((wv * 4 + g) * 4 + kb) * 64 + lane) * 8));
  float cc[4] = {0.f, 0.f, 0.f, 0.f};
  int nsteps = (kW - kd + d - 1) / d;
  half4 xr[4];
  {
    int mb = kd * 16 + ib;
#pragma unroll
    for (int g = 0; g < 4; ++g)
      xr[g] = *(const half4*)(Xfr + (((size_t)mb * 32 + (wv * 4 + g)) * 64 + lane) * 4);
  }
  for (int j = 0; j < nsteps; ++j) {
    floatx4 acc[4];
#pragma unroll
    for (int g = 0; g < 4; ++g)
      acc[g] = (floatx4){(float)xr[g][0], (float)xr[g][1], (float)xr[g][2], (float)xr[g][3]};
    if (j > 0) {
#pragma unroll
      for (int kb = 0; kb < 4; ++kb) {
        int gran = (kb * 4 + kq) ^ m;
        half8 a = *(const half8*)(&hbuf[(j - 1) & 1][m * 128 + gran * 8]);
#pragma unroll
        for (int g = 0; g < 4; ++g)
          acc[g] = __builtin_amdgcn_mfma_f32_16x16x32_f16(a, whf[g][kb], acc[g], 0, 0, 0);
      }
    }
    if (j + 1 < nsteps) {  // prefetch next-step pre-gates
      int mb = ((j + 1) * d + kd) * 16 + ib;
#pragma unroll
      for (int g = 0; g < 4; ++g)
        xr[g] = *(const half4*)(Xfr + (((size_t)mb * 32 + (wv * 4 + g)) * 64 + lane) * 4);
    }
#pragma unroll
    for (int r = 0; r < 4; ++r) {
      float iv = fsig(acc[0][r]);
      float fv = fsig(acc[1][r]);
      float g2 = fsig(acc[2][r]);  // sigmoid(2*g) ; tanh(g) = 2*g2-1
      float ov = fsig(acc[3][r]);
      cc[r] = fv * cc[r] + iv * (2.0f * g2 - 1.0f);
      float tc = 2.0f * fsig(cc[r] * (2.0f * kLOG2E)) - 1.0f;
      float hv = ov * tc;
      int brow = kq * 4 + r;
      int hu = wv * 16 + m;
      int gran = (hu >> 3) ^ brow;
      hbuf[j & 1][brow * 128 + gran * 8 + (hu & 7)] = (_Float16)hv;
    }
    __syncthreads();
    {  // stream h tile to global H (row-major [r][128] f16)
      int hr = tid >> 5, hu0 = (tid & 31) * 4;
      int gran = (hu0 >> 3) ^ hr;
      half4 hv4 = *(const half4*)(&hbuf[j & 1][hr * 128 + gran * 8 + (hu0 & 7)]);
      int wt = j * d + kd;
      *(half4*)(Hout + ((size_t)(wt * kB + ib * 16 + hr)) * kH + hu0) = hv4;
    }
  }
}

// ---------------- tail: outputs 2, 4, 5 ----------------
__global__ void k_tail(const float* __restrict__ out3, const float* __restrict__ val,
                       const float* __restrict__ seas, const float* __restrict__ levs,
                       float* __restrict__ out2, float* __restrict__ out4,
                       float* __restrict__ out5) {
  int idx = blockIdx.x * 256 + threadIdx.x;
  int b = idx / kOUT, j = idx % kOUT;
  float s = seas[(kT + j) * kB + b];
  float L = levs[(kT - 1) * kB + b];
  float net = out3[(size_t)(kW - 1) * kB * kOUT + idx];
  float hp = net * s * L;
  out2[idx] = hp > 0.0f ? hp : 0.0f;
  float v = val[idx];
  out4[idx] = v;
  out5[idx] = v / s / L;
}

extern "C" void kernel_launch(void* const* d_in, const int* in_sizes, int n_in, void* d_out,
                              int out_size, void* d_ws, size_t ws_size, hipStream_t stream) {
  const float* train = (const float*)d_in[0];
  const float* val = (const float*)d_in[1];
  const float* levp = (const float*)d_in[3];
  const float* seasp = (const float*)d_in[4];
  const float* inits = (const float*)d_in[5];
  const float* w_ih[4] = {(const float*)d_in[6], (const float*)d_in[10], (const float*)d_in[14],
                          (const float*)d_in[18]};
  const float* w_hh[4] = {(const float*)d_in[7], (const float*)d_in[11], (const float*)d_in[15],
                          (const float*)d_in[19]};
  const float* b_ih[4] = {(const float*)d_in[8], (const float*)d_in[12], (const float*)d_in[16],
                          (const float*)d_in[20]};
  const float* b_hh[4] = {(const float*)d_in[9], (const float*)d_in[13], (const float*)d_in[17],
                          (const float*)d_in[21]};
  const float* nl_w = (const float*)d_in[22];
  const float* nl_b = (const float*)d_in[23];
  const float* sc_w = (const float*)d_in[24];
  const float* sc_b = (const float*)d_in[25];

  char* wsb = (char*)d_ws;
  size_t off = 0;
  auto alloc = [&](size_t bytes) -> void* {
    void* p = wsb + off;
    off = (off + bytes + 255) & ~(size_t)255;
    return p;
  };
  float* trainT = (float*)alloc((size_t)kT * kB * 4);
  float* seas = (float*)alloc((size_t)560 * kB * 4);
  float* levs = (float*)alloc((size_t)kT * kB * 4);
  _Float16* win = (_Float16*)alloc((size_t)kNB * 64 * 2);
  _Float16* Xfr = (_Float16*)alloc((size_t)kMBLK * 32 * 64 * 4 * 2);
  _Float16* Hc[4];
  for (int c = 0; c < 4; ++c) Hc[c] = (_Float16*)alloc((size_t)kNB * kH * 2);
  float* biasp[4];
  for (int c = 0; c < 4; ++c) biasp[c] = (float*)alloc(512 * 4);
  _Float16* wihf[4];
  wihf[0] = (_Float16*)alloc((size_t)32 * 2 * 512 * 2);
  for (int c = 1; c < 4; ++c) wihf[c] = (_Float16*)alloc((size_t)32 * 4 * 512 * 2);
  _Float16* whhf[4];
  for (int c = 0; c < 4; ++c) whhf[c] = (_Float16*)alloc((size_t)32 * 4 * 512 * 2);
  _Float16* nlf = (_Float16*)alloc((size_t)8 * 4 * 512 * 2);
  _Float16* scf = (_Float16*)alloc((size_t)3 * 4 * 512 * 2);

  float* out0 = (float*)d_out;                       // network_pred (417,256,48)
  float* out1 = out0 + (size_t)kWO * kB * kOUT;      // network_act  (417,256,48)
  float* out2 = out1 + (size_t)kWO * kB * kOUT;      // hold_out_pred (256,48)
  float* out3 = out2 + (size_t)kB * kOUT;            // net_out_all  (465,256,48)
  float* out4 = out3 + (size_t)kW * kB * kOUT;       // hold_out_act (256,48)
  float* out5 = out4 + (size_t)kB * kOUT;            // hold_out_act_norm (256,48)

  k_transpose<<<kT, kB, 0, stream>>>(train, trainT);
  k_es<<<1, kB, 0, stream>>>(trainT, levp, seasp, inits, seas, levs);
  k_win_in<<<kW, kB, 0, stream>>>(trainT, seas, levs, win);
  k_win_out<<<kWO, kB, 0, stream>>>(trainT, seas, levs, out1);
  for (int c = 0; c < 4; ++c) k_prep_bias<<<2, 256, 0, stream>>>(b_ih[c], b_hh[c], biasp[c]);
  k_prep_frags<<<128, 256, 0, stream>>>(w_ih[0], wihf[0], 32, 2, 48, 48, 1);
  for (int c = 1; c < 4; ++c)
    k_prep_frags<<<256, 256, 0, stream>>>(w_ih[c], wihf[c], 32, 4, 128, 128, 1);
  for (int c = 0; c < 4; ++c)
    k_prep_frags<<<256, 256, 0, stream>>>(w_hh[c], whhf[c], 32, 4, 128, 128, 1);
  k_prep_frags<<<64, 256, 0, stream>>>(nl_w, nlf, 8, 4, 128, 128, 0);
  k_prep_frags<<<24, 256, 0, stream>>>(sc_w, scf, 3, 4, 128, 128, 0);

  const int GG = kMBLK / 8;  // 930
  k_gemm<32, 2, 0><<<GG, 512, 0, stream>>>(win, nullptr, 64, wihf[0], biasp[0], Xfr, nullptr, nullptr);
  k_rec<<<16, 512, 0, stream>>>(Xfr, whhf[0], Hc[0], 1);
  k_gemm<32, 4, 0><<<GG, 512, 0, stream>>>(Hc[0], nullptr, 128, wihf[1], biasp[1], Xfr, nullptr, nullptr);
  k_rec<<<32, 512, 0, stream>>>(Xfr, whhf[1], Hc[1], 2);
  k_gemm<32, 4, 0><<<GG, 512, 0, stream>>>(Hc[1], nullptr, 128, wihf[2], biasp[2], Xfr, nullptr, nullptr);
  k_rec<<<64, 512, 0, stream>>>(Xfr, whhf[2], Hc[2], 4);
  k_gemm<32, 4, 0><<<GG, 512, 0, stream>>>(Hc[2], nullptr, 128, wihf[3], biasp[3], Xfr, nullptr, nullptr);
  k_rec<<<128, 512, 0, stream>>>(Xfr, whhf[3], Hc[3], 8);
  // nl: A = H4 + H2 (residual), tanh -> U (reuse Hc[0], dead after cell1 pre-GEMM)
  k_gemm<8, 4, 1><<<GG, 512, 0, stream>>>(Hc[3], Hc[1], 128, nlf, nl_b, Hc[0], nullptr, nullptr);
  // sc: f32 out -> net_out_all (out3) + network_pred (out0 = rows < 417*256)
  k_gemm<3, 4, 2><<<GG, 512, 0, stream>>>(Hc[0], nullptr, 128, scf, sc_b, nullptr, out3, out0);
  k_tail<<<48, 256, 0, stream>>>(out3, val, seas, levs, out2, out4, out5);
}

// Round 2
// 1181.019 us; speedup vs baseline: 1.0947x; 1.0947x over previous
//
#include <hip/hip_runtime.h>
#include <cstdint>
#include <cstddef>

typedef _Float16 half8 __attribute__((ext_vector_type(8)));
typedef _Float16 half4 __attribute__((ext_vector_type(4)));
typedef float floatx4 __attribute__((ext_vector_type(4)));

namespace {
constexpr int kB = 256, kT = 512, kIN = 48, kOUT = 48, kSEAS = 24, kH = 128;
constexpr int kW = kT - kIN + 1;           // 465 windows
constexpr int kWO = kT - kOUT - kIN + 1;   // 417
constexpr int kNB = kW * kB;               // 119040 rows
constexpr int kMBLK = kNB / 16;            // 7440 row-blocks of 16
constexpr float kLOG2E = 1.44269504088896340736f;
}

#if __has_builtin(__builtin_amdgcn_exp2f)
#define FEXP2(x) __builtin_amdgcn_exp2f(x)
#else
#define FEXP2(x) exp2f(x)
#endif
#if __has_builtin(__builtin_amdgcn_rcpf)
#define FRCP(x) __builtin_amdgcn_rcpf(x)
#else
#define FRCP(x) (1.0f / (x))
#endif

// sigmoid in exp2-domain: fsig(y) = 1/(1+2^-y); pass y = x*log2(e) for sigmoid(x)
__device__ __forceinline__ float fsig(float y) { return FRCP(1.0f + FEXP2(-y)); }
__device__ __forceinline__ float ftanh(float x) { return 2.0f * fsig(2.0f * kLOG2E * x) - 1.0f; }

// ---------------- transpose train (B,T) -> (T,B) ----------------
__global__ void k_transpose(const float* __restrict__ train, float* __restrict__ trainT) {
  int t = blockIdx.x, b = threadIdx.x;
  trainT[t * kB + b] = train[b * kT + t];
}

// ---------------- exponential smoothing scan (LDS ring, no global RAW) ----------------
// seas laid out [560][B] (rows 0..24 head, 25..535 scan, 536..559 extension); levs [512][B]
__global__ void k_es(const float* __restrict__ trainT, const float* __restrict__ levp,
                     const float* __restrict__ seasp, const float* __restrict__ inits,
                     float* __restrict__ seas, float* __restrict__ levs) {
  __shared__ float ring[kSEAS][kB];  // ring[k % 24][b] holds st for step k (same-thread column)
  int b = threadIdx.x;
  float lev_sm = fsig(levp[0] * kLOG2E);
  float seas_sm = fsig(seasp[0] * kLOG2E);
  float s00 = expf(inits[0]);
  for (int s = 0; s < kSEAS; ++s) {
    float v = expf(inits[s]);
    seas[s * kB + b] = v;
    if (s >= 1) ring[s - 1][b] = v;  // st(k)=S[k+1] for k=0..22
  }
  ring[kSEAS - 1][b] = s00;  // st(23)=S[24]=s00
  seas[kSEAS * kB + b] = s00;
  float lev = trainT[b] * FRCP(s00);
  levs[b] = lev;
  int rk = 0;
  float x_nx = trainT[kB + b];
  float st_nx = ring[0][b];
  for (int k = 0; k < kT - 1; ++k) {
    float x = x_nx;
    float st = st_nx;
    if (k + 1 < kT - 1) x_nx = trainT[(k + 2) * kB + b];
    int rn = (rk + 1 == kSEAS) ? 0 : rk + 1;
    st_nx = ring[rn][b];  // st(k+1), written at step k-23 (or init)
    float ln = lev_sm * (x * FRCP(st)) + (1.0f - lev_sm) * lev;
    float sn = seas_sm * (x * FRCP(ln)) + (1.0f - seas_sm) * st;
    ring[rk][b] = sn;  // becomes st(k+24), same slot
    seas[(k + kSEAS + 1) * kB + b] = sn;
    levs[(k + 1) * kB + b] = ln;
    lev = ln;
    rk = rn;
  }
  for (int j = 0; j < kOUT - kSEAS; ++j)
    seas[(kT + kSEAS + j) * kB + b] = seas[(kT + j) * kB + b];
}

// ---------------- window build: win_in (f16, padded K=64), vectorized stores ----------------
__global__ void k_win_in(const float* __restrict__ trainT, const float* __restrict__ seas,
                         const float* __restrict__ levs, _Float16* __restrict__ win) {
  int w = blockIdx.x;
  int tid = threadIdx.x;
#pragma unroll
  for (int i = 0; i < 16; ++i) {
    int o = i * 256 + tid;   // half8 chunk index within this w (256 rows x 8 chunks)
    int b = o >> 3;
    int j0 = (o & 7) * 8;
    half8 h;
    if (j0 < kIN) {
      float rl = FRCP(levs[(kIN - 1 + w) * kB + b]);
#pragma unroll
      for (int jj = 0; jj < 8; ++jj) {
        int j = j0 + jj;
        int t = w + j;
        float v = (j < kIN) ? trainT[t * kB + b] * FRCP(seas[t * kB + b]) * rl : 0.0f;
        h[jj] = (_Float16)v;
      }
    } else {
#pragma unroll
      for (int jj = 0; jj < 8; ++jj) h[jj] = (_Float16)0.0f;
    }
    *(half8*)(win + ((size_t)(w * kB + b)) * 64 + j0) = h;
  }
}

// ---------------- window build: win_out == output 1 (fp32), float4 stores ----------------
__global__ void k_win_out(const float* __restrict__ trainT, const float* __restrict__ seas,
                          const float* __restrict__ levs, float* __restrict__ out1) {
  int idx = blockIdx.x * 256 + threadIdx.x;  // float4 index
  if (idx >= kWO * kB * (kOUT / 4)) return;
  int row = idx / 12;
  int j0 = (idx - row * 12) * 4;
  int wo = row >> 8;
  int b = row & 255;
  float rl = FRCP(levs[(kIN - 1 + wo) * kB + b]);
  floatx4 v;
#pragma unroll
  for (int jj = 0; jj < 4; ++jj) {
    int t = kIN + wo + j0 + jj;
    v[jj] = trainT[t * kB + b] * FRCP(seas[t * kB + b]) * rl;
  }
  *(floatx4*)(out1 + (size_t)row * kOUT + j0) = v;
}

// ---------------- weight prep ----------------
__global__ void k_prep_bias(const float* __restrict__ bih, const float* __restrict__ bhh,
                            float* __restrict__ dst) {
  int c = blockIdx.x * 256 + threadIdx.x;
  if (c >= 512) return;
  int ct = c >> 4, n16 = c & 15, g = ct & 3, wv = ct >> 2;
  int row = g * 128 + wv * 16 + n16;
  float sc = (g == 2) ? 2.0f * kLOG2E : kLOG2E;
  dst[c] = (bih[row] + bhh[row]) * sc;
}

// B-fragment layout: [ct][kb][lane][jj] ; value = W[row(n)][k], n=lane&15, k=kb*32+(lane>>4)*8+jj
__global__ void k_prep_frags(const float* __restrict__ Wsrc, _Float16* __restrict__ dst, int NT,
                             int KB, int Kreal, int srcld, int perm) {
  int idx = blockIdx.x * 256 + threadIdx.x;
  int total = NT * KB * 512;
  if (idx >= total) return;
  int jj = idx & 7;
  int lane = (idx >> 3) & 63;
  int kb = (idx >> 9) % KB;
  int ct = idx / (KB * 512);
  int n16 = lane & 15;
  int k = kb * 32 + ((lane >> 4) << 3) + jj;
  int row;
  float sc;
  if (perm) {
    int g = ct & 3, wv = ct >> 2;
    row = g * 128 + wv * 16 + n16;
    sc = (g == 2) ? 2.0f * kLOG2E : kLOG2E;
  } else {
    row = ct * 16 + n16;
    sc = 1.0f;
  }
  float v = (k < Kreal) ? Wsrc[row * srcld + k] * sc : 0.0f;
  dst[idx] = (_Float16)v;
}

// ---------------- generic MFMA GEMM over the NB rows ----------------
template <int NT, int KB, int MODE>
__global__ __launch_bounds__(512) void k_gemm(const _Float16* __restrict__ A,
                                              const _Float16* __restrict__ A2, int Khalfs,
                                              const _Float16* __restrict__ Bfr,
                                              const float* __restrict__ bias,
                                              _Float16* __restrict__ outh,
                                              float* __restrict__ outf,
                                              float* __restrict__ outf2) {
  __shared__ _Float16 bsh[NT * KB * 512];
  int tid = threadIdx.x;
  {
    const uint4* src = (const uint4*)Bfr;
    uint4* dst = (uint4*)bsh;
    for (int i = tid; i < NT * KB * 64; i += 512) dst[i] = src[i];
  }
  __syncthreads();
  int wv = tid >> 6, lane = tid & 63;
  int mblk = blockIdx.x * 8 + wv;
  if (mblk >= kMBLK) return;
  int m = lane & 15, kq = lane >> 4;
  const _Float16* arow = A + (size_t)(mblk * 16 + m) * Khalfs + kq * 8;
  half8 af[KB];
#pragma unroll
  for (int kb = 0; kb < KB; ++kb) af[kb] = *(const half8*)(arow + kb * 32);
  if constexpr (MODE == 1) {
    const _Float16* arow2 = A2 + (size_t)(mblk * 16 + m) * Khalfs + kq * 8;
#pragma unroll
    for (int kb = 0; kb < KB; ++kb) {
      half8 a2 = *(const half8*)(arow2 + kb * 32);
      af[kb] += a2;
    }
  }
#pragma unroll
  for (int t0 = 0; t0 < NT; t0 += 2) {
    float b0 = bias[t0 * 16 + m];
    floatx4 acc0 = {b0, b0, b0, b0};
    floatx4 acc1 = {0.f, 0.f, 0.f, 0.f};
    if (t0 + 1 < NT) {
      float b1 = bias[(t0 + 1) * 16 + m];
      acc1 = (floatx4){b1, b1, b1, b1};
    }
#pragma unroll
    for (int kb = 0; kb < KB; ++kb) {
      half8 bf0 = *(const half8*)(&bsh[((t0 * KB + kb) * 64 + lane) * 8]);
      acc0 = __builtin_amdgcn_mfma_f32_16x16x32_f16(af[kb], bf0, acc0, 0, 0, 0);
      if (t0 + 1 < NT) {
        half8 bf1 = *(const half8*)(&bsh[(((t0 + 1) * KB + kb) * 64 + lane) * 8]);
        acc1 = __builtin_amdgcn_mfma_f32_16x16x32_f16(af[kb], bf1, acc1, 0, 0, 0);
      }
    }
    if constexpr (MODE == 0) {
      half4 h0 = {(_Float16)acc0[0], (_Float16)acc0[1], (_Float16)acc0[2], (_Float16)acc0[3]};
      *(half4*)(outh + (((size_t)mblk * NT + t0) * 64 + lane) * 4) = h0;
      if (t0 + 1 < NT) {
        half4 h1 = {(_Float16)acc1[0], (_Float16)acc1[1], (_Float16)acc1[2], (_Float16)acc1[3]};
        *(half4*)(outh + (((size_t)mblk * NT + (t0 + 1)) * 64 + lane) * 4) = h1;
      }
    } else if constexpr (MODE == 1) {
#pragma unroll
      for (int r = 0; r < 4; ++r) {
        int row = mblk * 16 + kq * 4 + r;
        outh[(size_t)row * kH + t0 * 16 + m] = (_Float16)ftanh(acc0[r]);
        if (t0 + 1 < NT) outh[(size_t)row * kH + (t0 + 1) * 16 + m] = (_Float16)ftanh(acc1[r]);
      }
    } else {
#pragma unroll
      for (int r = 0; r < 4; ++r) {
        int row = mblk * 16 + kq * 4 + r;
        float v0 = acc0[r];
        outf[(size_t)row * kOUT + t0 * 16 + m] = v0;
        if (row < kWO * kB) outf2[(size_t)row * kOUT + t0 * 16 + m] = v0;
        if (t0 + 1 < NT) {
          float v1 = acc1[r];
          outf[(size_t)row * kOUT + (t0 + 1) * 16 + m] = v1;
          if (row < kWO * kB) outf2[(size_t)row * kOUT + (t0 + 1) * 16 + m] = v1;
        }
      }
    }
  }
}

// ---------------- recurrent LSTM kernel ----------------
// One step; PHASE = j&1 baked at compile time (even: writes hbuf[0], reads hbuf[1]).
// xu = pre-gates for this step (already loaded); xf gets prefetch for step j+2.
struct XR { half4 v[4]; };

template <int PHASE>
__device__ __forceinline__ void rec_step(int j, int nsteps, int d, int kd, int ib, int wv,
                                         int lane, int m, int kq, int tid,
                                         const _Float16* __restrict__ Xfr,
                                         _Float16* __restrict__ Hout,
                                         const half8 (&whf)[4][4], float (&cc)[4], XR& xu,
                                         XR& xf, _Float16 (*hbuf)[2048]) {
  floatx4 acc[4];
#pragma unroll
  for (int g = 0; g < 4; ++g)
    acc[g] = (floatx4){(float)xu.v[g][0], (float)xu.v[g][1], (float)xu.v[g][2], (float)xu.v[g][3]};
  if (j + 2 < nsteps) {  // depth-2 prefetch (parity buffers: no reg copy, 2 steps of latency)
    int mb = ((j + 2) * d + kd) * 16 + ib;
#pragma unroll
    for (int g = 0; g < 4; ++g)
      xf.v[g] = *(const half4*)(Xfr + (((size_t)mb * 32 + (wv * 4 + g)) * 64 + lane) * 4);
  }
  if (j > 0) {
#pragma unroll
    for (int kb = 0; kb < 4; ++kb) {
      int gran = (kb * 4 + kq) ^ m;
      half8 a = *(const half8*)(&hbuf[PHASE ^ 1][m * 128 + gran * 8]);
#pragma unroll
      for (int g = 0; g < 4; ++g)
        acc[g] = __builtin_amdgcn_mfma_f32_16x16x32_f16(a, whf[g][kb], acc[g], 0, 0, 0);
    }
  }
#pragma unroll
  for (int r = 0; r < 4; ++r) {
    float iv = fsig(acc[0][r]);
    float fv = fsig(acc[1][r]);
    float g2 = fsig(acc[2][r]);  // sigmoid(2*g); tanh(g) = 2*g2-1
    float ov = fsig(acc[3][r]);
    cc[r] = fv * cc[r] + iv * (2.0f * g2 - 1.0f);
    float tc = 2.0f * fsig(cc[r] * (2.0f * kLOG2E)) - 1.0f;
    float hv = ov * tc;
    int brow = kq * 4 + r;
    int hu = wv * 16 + m;
    int gran = (hu >> 3) ^ brow;
    hbuf[PHASE][brow * 128 + gran * 8 + (hu & 7)] = (_Float16)hv;
  }
  // LDS-only barrier: do NOT drain vmcnt (keeps Hout stores + Xfr prefetch in flight)
  asm volatile("s_waitcnt lgkmcnt(0)\n\ts_barrier" ::: "memory");
  {
    int hr = tid >> 5, hu0 = (tid & 31) * 4;
    int gran = (hu0 >> 3) ^ hr;
    half4 hv4 = *(const half4*)(&hbuf[PHASE][hr * 128 + gran * 8 + (hu0 & 7)]);
    int wt = j * d + kd;
    *(half4*)(Hout + ((size_t)(wt * kB + ib * 16 + hr)) * kH + hu0) = hv4;
  }
}

__global__ __launch_bounds__(512) void k_rec(const _Float16* __restrict__ Xfr,
                                             const _Float16* __restrict__ Whhf,
                                             _Float16* __restrict__ Hout, int d) {
  __shared__ _Float16 hbuf[2][2048];
  int tid = threadIdx.x, wv = tid >> 6, lane = tid & 63;
  int kd = blockIdx.x >> 4, ib = blockIdx.x & 15;
  int m = lane & 15, kq = lane >> 4;
  half8 whf[4][4];
#pragma unroll
  for (int g = 0; g < 4; ++g)
#pragma unroll
    for (int kb = 0; kb < 4; ++kb)
      whf[g][kb] = *(const half8*)(Whhf + ((((wv * 4 + g) * 4 + kb) * 64 + lane) * 8));
  float cc[4] = {0.f, 0.f, 0.f, 0.f};
  int nsteps = (kW - kd + d - 1) / d;
  XR xa, xb;
  {
    int mb = kd * 16 + ib;
#pragma unroll
    for (int g = 0; g < 4; ++g)
      xa.v[g] = *(const half4*)(Xfr + (((size_t)mb * 32 + (wv * 4 + g)) * 64 + lane) * 4);
  }
  if (1 < nsteps) {
    int mb = (d + kd) * 16 + ib;
#pragma unroll
    for (int g = 0; g < 4; ++g)
      xb.v[g] = *(const half4*)(Xfr + (((size_t)mb * 32 + (wv * 4 + g)) * 64 + lane) * 4);
  }
  for (int j = 0; j < nsteps; j += 2) {
    rec_step<0>(j, nsteps, d, kd, ib, wv, lane, m, kq, tid, Xfr, Hout, whf, cc, xa, xa, hbuf);
    if (j + 1 < nsteps)
      rec_step<1>(j + 1, nsteps, d, kd, ib, wv, lane, m, kq, tid, Xfr, Hout, whf, cc, xb, xb,
                  hbuf);
  }
}

// ---------------- tail: outputs 2, 4, 5 ----------------
__global__ void k_tail(const float* __restrict__ out3, const float* __restrict__ val,
                       const float* __restrict__ seas, const float* __restrict__ levs,
                       float* __restrict__ out2, float* __restrict__ out4,
                       float* __restrict__ out5) {
  int idx = blockIdx.x * 256 + threadIdx.x;
  int b = idx / kOUT, j = idx % kOUT;
  float s = seas[(kT + j) * kB + b];
  float L = levs[(kT - 1) * kB + b];
  float net = out3[(size_t)(kW - 1) * kB * kOUT + idx];
  float hp = net * s * L;
  out2[idx] = hp > 0.0f ? hp : 0.0f;
  float v = val[idx];
  out4[idx] = v;
  out5[idx] = v / s / L;
}

extern "C" void kernel_launch(void* const* d_in, const int* in_sizes, int n_in, void* d_out,
                              int out_size, void* d_ws, size_t ws_size, hipStream_t stream) {
  const float* train = (const float*)d_in[0];
  const float* val = (const float*)d_in[1];
  const float* levp = (const float*)d_in[3];
  const float* seasp = (const float*)d_in[4];
  const float* inits = (const float*)d_in[5];
  const float* w_ih[4] = {(const float*)d_in[6], (const float*)d_in[10], (const float*)d_in[14],
                          (const float*)d_in[18]};
  const float* w_hh[4] = {(const float*)d_in[7], (const float*)d_in[11], (const float*)d_in[15],
                          (const float*)d_in[19]};
  const float* b_ih[4] = {(const float*)d_in[8], (const float*)d_in[12], (const float*)d_in[16],
                          (const float*)d_in[20]};
  const float* b_hh[4] = {(const float*)d_in[9], (const float*)d_in[13], (const float*)d_in[17],
                          (const float*)d_in[21]};
  const float* nl_w = (const float*)d_in[22];
  const float* nl_b = (const float*)d_in[23];
  const float* sc_w = (const float*)d_in[24];
  const float* sc_b = (const float*)d_in[25];

  char* wsb = (char*)d_ws;
  size_t off = 0;
  auto alloc = [&](size_t bytes) -> void* {
    void* p = wsb + off;
    off = (off + bytes + 255) & ~(size_t)255;
    return p;
  };
  float* trainT = (float*)alloc((size_t)kT * kB * 4);
  float* seas = (float*)alloc((size_t)560 * kB * 4);
  float* levs = (float*)alloc((size_t)kT * kB * 4);
  _Float16* win = (_Float16*)alloc((size_t)kNB * 64 * 2);
  _Float16* Xfr = (_Float16*)alloc((size_t)kMBLK * 32 * 64 * 4 * 2);
  _Float16* Hc[4];
  for (int c = 0; c < 4; ++c) Hc[c] = (_Float16*)alloc((size_t)kNB * kH * 2);
  float* biasp[4];
  for (int c = 0; c < 4; ++c) biasp[c] = (float*)alloc(512 * 4);
  _Float16* wihf[4];
  wihf[0] = (_Float16*)alloc((size_t)32 * 2 * 512 * 2);
  for (int c = 1; c < 4; ++c) wihf[c] = (_Float16*)alloc((size_t)32 * 4 * 512 * 2);
  _Float16* whhf[4];
  for (int c = 0; c < 4; ++c) whhf[c] = (_Float16*)alloc((size_t)32 * 4 * 512 * 2);
  _Float16* nlf = (_Float16*)alloc((size_t)8 * 4 * 512 * 2);
  _Float16* scf = (_Float16*)alloc((size_t)3 * 4 * 512 * 2);

  float* out0 = (float*)d_out;                     // network_pred (417,256,48)
  float* out1 = out0 + (size_t)kWO * kB * kOUT;    // network_act  (417,256,48)
  float* out2 = out1 + (size_t)kWO * kB * kOUT;    // hold_out_pred (256,48)
  float* out3 = out2 + (size_t)kB * kOUT;          // net_out_all  (465,256,48)
  float* out4 = out3 + (size_t)kW * kB * kOUT;     // hold_out_act (256,48)
  float* out5 = out4 + (size_t)kB * kOUT;          // hold_out_act_norm (256,48)

  k_transpose<<<kT, kB, 0, stream>>>(train, trainT);
  k_es<<<1, kB, 0, stream>>>(trainT, levp, seasp, inits, seas, levs);
  k_win_in<<<kW, kB, 0, stream>>>(trainT, seas, levs, win);
  k_win_out<<<(kWO * kB * 12 + 255) / 256, 256, 0, stream>>>(trainT, seas, levs, out1);
  for (int c = 0; c < 4; ++c) k_prep_bias<<<2, 256, 0, stream>>>(b_ih[c], b_hh[c], biasp[c]);
  k_prep_frags<<<128, 256, 0, stream>>>(w_ih[0], wihf[0], 32, 2, 48, 48, 1);
  for (int c = 1; c < 4; ++c)
    k_prep_frags<<<256, 256, 0, stream>>>(w_ih[c], wihf[c], 32, 4, 128, 128, 1);
  for (int c = 0; c < 4; ++c)
    k_prep_frags<<<256, 256, 0, stream>>>(w_hh[c], whhf[c], 32, 4, 128, 128, 1);
  k_prep_frags<<<64, 256, 0, stream>>>(nl_w, nlf, 8, 4, 128, 128, 0);
  k_prep_frags<<<24, 256, 0, stream>>>(sc_w, scf, 3, 4, 128, 128, 0);

  const int GG = kMBLK / 8;  // 930
  k_gemm<32, 2, 0><<<GG, 512, 0, stream>>>(win, nullptr, 64, wihf[0], biasp[0], Xfr, nullptr, nullptr);
  k_rec<<<16, 512, 0, stream>>>(Xfr, whhf[0], Hc[0], 1);
  k_gemm<32, 4, 0><<<GG, 512, 0, stream>>>(Hc[0], nullptr, 128, wihf[1], biasp[1], Xfr, nullptr, nullptr);
  k_rec<<<32, 512, 0, stream>>>(Xfr, whhf[1], Hc[1], 2);
  k_gemm<32, 4, 0><<<GG, 512, 0, stream>>>(Hc[1], nullptr, 128, wihf[2], biasp[2], Xfr, nullptr, nullptr);
  k_rec<<<64, 512, 0, stream>>>(Xfr, whhf[2], Hc[2], 4);
  k_gemm<32, 4, 0><<<GG, 512, 0, stream>>>(Hc[2], nullptr, 128, wihf[3], biasp[3], Xfr, nullptr, nullptr);
  k_rec<<<128, 512, 0, stream>>>(Xfr, whhf[3], Hc[3], 8);
  // nl: A = H4 + H2 (residual), tanh -> U (reuse Hc[0], dead after cell1 pre-GEMM)
  k_gemm<8, 4, 1><<<GG, 512, 0, stream>>>(Hc[3], Hc[1], 128, nlf, nl_b, Hc[0], nullptr, nullptr);
  // sc: f32 out -> net_out_all (out3) + network_pred (out0 = rows < 417*256)
  k_gemm<3, 4, 2><<<GG, 512, 0, stream>>>(Hc[0], nullptr, 128, scf, sc_b, nullptr, out3, out0);
  k_tail<<<48, 256, 0, stream>>>(out3, val, seas, levs, out2, out4, out5);
}